// Round 1
// baseline (983.249 us; speedup 1.0000x reference)
//
#include <hip/hip_runtime.h>
#include <hip/hip_bf16.h>
#include <math.h>

// Problem dims (fixed by reference)
#define BB 4
#define TT 1024
#define DD 1024
#define HPS 4          // heads per scale
#define HD 256         // head_dim = D / HPS
#define C0 21
#define C1 41
#define N0 (HPS * C0)  // 84
#define N1 (HPS * C1)  // 164
#define BT (BB * TT)   // 4096

// ---------------- Tiled fp32 GEMM: C[M,N] = op(A)[M,K] @ B[K,N] ----------------
// BM=BN=64, BK=16, 256 threads, 4x4 per thread register tile.
#define BM 64
#define BN 64
#define BK 16

template <bool RELU>
__global__ __launch_bounds__(256) void gemm_f32(
    const float* __restrict__ A, int lda,
    const float* __restrict__ B, int ldb,
    float* __restrict__ C, int ldc,
    int M, int N, int K)
{
    __shared__ float As[BK][BM + 1];
    __shared__ float Bs[BK][BN + 1];

    const int block_row = blockIdx.y * BM;
    const int block_col = blockIdx.x * BN;
    const int tid = threadIdx.x;
    const int tr = tid >> 4;   // 0..15
    const int tc = tid & 15;   // 0..15

    float acc[4][4] = {};

    for (int k0 = 0; k0 < K; k0 += BK) {
        // Load A tile: BM x BK (64x16). 256 threads x 4 elements.
        #pragma unroll
        for (int i = 0; i < 4; i++) {
            int e = tid + i * 256;
            int r = e >> 4;      // 0..63
            int c = e & 15;      // 0..15
            int gr = block_row + r;
            int gk = k0 + c;
            float v = A[(size_t)gr * lda + gk];   // M=4096 multiple of 64, K mult of 16
            if (RELU) v = fmaxf(v, 0.0f);
            As[c][r] = v;
        }
        // Load B tile: BK x BN (16x64).
        #pragma unroll
        for (int i = 0; i < 4; i++) {
            int e = tid + i * 256;
            int r = e >> 6;      // 0..15
            int c = e & 63;      // 0..63
            int gk = k0 + r;
            int gc = block_col + c;
            Bs[r][c] = (gc < N) ? B[(size_t)gk * ldb + gc] : 0.0f;
        }
        __syncthreads();

        #pragma unroll
        for (int kk = 0; kk < BK; kk++) {
            float a[4], b[4];
            #pragma unroll
            for (int i = 0; i < 4; i++) a[i] = As[kk][tr * 4 + i];
            #pragma unroll
            for (int j = 0; j < 4; j++) b[j] = Bs[kk][tc * 4 + j];
            #pragma unroll
            for (int i = 0; i < 4; i++)
                #pragma unroll
                for (int j = 0; j < 4; j++)
                    acc[i][j] = fmaf(a[i], b[j], acc[i][j]);
        }
        __syncthreads();
    }

    #pragma unroll
    for (int i = 0; i < 4; i++) {
        int gr = block_row + tr * 4 + i;
        #pragma unroll
        for (int j = 0; j < 4; j++) {
            int gc = block_col + tc * 4 + j;
            if (gc < N) C[(size_t)gr * ldc + gc] = acc[i][j];
        }
    }
}

// ------------- Fused per-(b,t) softmax + sliding-window weighted sum -------------
// One block per (b,t), 256 threads; thread d4 computes x[b,t, 4*d4 .. 4*d4+3].
__global__ __launch_bounds__(256) void attn_window_kernel(
    const float* __restrict__ qv,        // [B,T,2D], v = qv[...,D:]
    const float* __restrict__ logits0,   // [B*T, N0]
    const float* __restrict__ logits1,   // [B*T, N1]
    const float* __restrict__ scale_w,   // [2]
    float* __restrict__ x)               // [B,T,D]
{
    const int bt = blockIdx.x;
    const int b = bt >> 10;       // T = 1024
    const int t = bt & 1023;

    __shared__ float a0[HPS][C0];
    __shared__ float a1[HPS][C1];
    __shared__ float sw[2];

    const int tid = threadIdx.x;

    if (tid == 0) {
        float s0 = scale_w[0], s1 = scale_w[1];
        float m = fmaxf(s0, s1);
        float e0 = __expf(s0 - m), e1 = __expf(s1 - m);
        float inv = 1.0f / (e0 + e1);
        sw[0] = e0 * inv;
        sw[1] = e1 * inv;
    }

    if (tid < HPS) {
        // softmax over 21 for head tid (scale 0)
        const float* L = logits0 + (size_t)bt * N0 + tid * C0;
        float m = -1e30f;
        for (int j = 0; j < C0; j++) m = fmaxf(m, L[j]);
        float s = 0.0f;
        for (int j = 0; j < C0; j++) s += __expf(L[j] - m);
        float inv = 1.0f / s;
        for (int j = 0; j < C0; j++) a0[tid][j] = __expf(L[j] - m) * inv;
    } else if (tid >= HPS && tid < 2 * HPS) {
        int h = tid - HPS;
        const float* L = logits1 + (size_t)bt * N1 + h * C1;
        float m = -1e30f;
        for (int j = 0; j < C1; j++) m = fmaxf(m, L[j]);
        float s = 0.0f;
        for (int j = 0; j < C1; j++) s += __expf(L[j] - m);
        float inv = 1.0f / s;
        for (int j = 0; j < C1; j++) a1[h][j] = __expf(L[j] - m) * inv;
    }
    __syncthreads();

    const int d = tid * 4;          // 4 consecutive floats per thread
    const int h = d >> 8;           // head index (head_dim = 256)
    const float sw0 = sw[0], sw1 = sw[1];
    // v[b, tt, :] lives at qv + ((b*T + tt) * 2D) + D
    const float* vbase = qv + (size_t)b * TT * (2 * DD) + DD + d;

    float4 acc = make_float4(0.f, 0.f, 0.f, 0.f);

    #pragma unroll
    for (int j = 0; j < C0; j++) {
        int tt = t + j - (C0 - 1) / 2;
        if (tt < 0 || tt >= TT) continue;
        float w = sw0 * a0[h][j];
        float4 vv = *(const float4*)(vbase + (size_t)tt * (2 * DD));
        acc.x = fmaf(w, vv.x, acc.x);
        acc.y = fmaf(w, vv.y, acc.y);
        acc.z = fmaf(w, vv.z, acc.z);
        acc.w = fmaf(w, vv.w, acc.w);
    }
    #pragma unroll
    for (int j = 0; j < C1; j++) {
        int tt = t + j - (C1 - 1) / 2;
        if (tt < 0 || tt >= TT) continue;
        float w = sw1 * a1[h][j];
        float4 vv = *(const float4*)(vbase + (size_t)tt * (2 * DD));
        acc.x = fmaf(w, vv.x, acc.x);
        acc.y = fmaf(w, vv.y, acc.y);
        acc.z = fmaf(w, vv.z, acc.z);
        acc.w = fmaf(w, vv.w, acc.w);
    }

    *(float4*)(x + (size_t)bt * DD + d) = acc;
}

// ---------------------------------- launch ----------------------------------
extern "C" void kernel_launch(void* const* d_in, const int* in_sizes, int n_in,
                              void* d_out, int out_size, void* d_ws, size_t ws_size,
                              hipStream_t stream)
{
    const float* query   = (const float*)d_in[0];
    // d_in[1] = key   (unused by reference)
    // d_in[2] = value (unused by reference)
    const float* W_qv    = (const float*)d_in[3];
    const float* W2_0    = (const float*)d_in[4];
    const float* W2_1    = (const float*)d_in[5];
    const float* scale_w = (const float*)d_in[6];
    const float* W_out   = (const float*)d_in[7];
    float* out = (float*)d_out;

    // Workspace layout (floats)
    float* ws = (float*)d_ws;
    float* qv      = ws;                                   // BT * 2D  = 8,388,608
    float* x       = qv + (size_t)BT * 2 * DD;             // BT * D   = 4,194,304
    float* logits0 = x + (size_t)BT * DD;                  // BT * N0  =   344,064
    float* logits1 = logits0 + (size_t)BT * N0;            // BT * N1  =   671,744

    // 1) qv = query @ W_qv    [4096,1024] x [1024,2048]
    {
        dim3 grid((2 * DD) / BN, BT / BM);
        gemm_f32<false><<<grid, 256, 0, stream>>>(query, DD, W_qv, 2 * DD,
                                                  qv, 2 * DD, BT, 2 * DD, DD);
    }
    // 2a) logits0 = relu(q) @ W2_0   [4096,1024] x [1024,84]
    {
        dim3 grid((N0 + BN - 1) / BN, BT / BM);
        gemm_f32<true><<<grid, 256, 0, stream>>>(qv, 2 * DD, W2_0, N0,
                                                 logits0, N0, BT, N0, DD);
    }
    // 2b) logits1 = relu(q) @ W2_1   [4096,1024] x [1024,164]
    {
        dim3 grid((N1 + BN - 1) / BN, BT / BM);
        gemm_f32<true><<<grid, 256, 0, stream>>>(qv, 2 * DD, W2_1, N1,
                                                 logits1, N1, BT, N1, DD);
    }
    // 3) softmax + sliding-window weighted sum -> x
    {
        attn_window_kernel<<<BT, 256, 0, stream>>>(qv, logits0, logits1, scale_w, x);
    }
    // 4) out = x @ W_out   [4096,1024] x [1024,1024]
    {
        dim3 grid(DD / BN, BT / BM);
        gemm_f32<false><<<grid, 256, 0, stream>>>(x, DD, W_out, DD,
                                                  out, DD, BT, DD, DD);
    }
}

// Round 2
// 340.894 us; speedup vs baseline: 2.8843x; 2.8843x over previous
//
#include <hip/hip_runtime.h>
#include <hip/hip_bf16.h>
#include <math.h>

// Problem dims (fixed by reference)
#define BB 4
#define TT 1024
#define DD 1024
#define HPS 4          // heads per scale
#define C0 21
#define C1 41
#define N0 (HPS * C0)  // 84
#define N1 (HPS * C1)  // 164
#define NL 256         // padded combined logits width (84 + 164 = 248 -> 256)
#define BT (BB * TT)   // 4096

typedef unsigned int uint;
typedef __bf16 bf16x8 __attribute__((ext_vector_type(8)));
typedef float f32x4 __attribute__((ext_vector_type(4)));

__device__ __forceinline__ ushort f2bf(float f) {
    union { float f; uint u; } v; v.f = f;
    uint u = v.u;
    uint r = (u + 0x7FFFu + ((u >> 16) & 1u)) >> 16;
    return (ushort)r;
}

// ---------------- fp32 -> bf16 row copy (query) ----------------
__global__ __launch_bounds__(256) void f32_to_bf16(const float* __restrict__ in,
                                                   ushort* __restrict__ out, int n) {
    int i = (blockIdx.x * 256 + threadIdx.x) * 4;
    if (i < n) {
        float4 v = *(const float4*)(in + i);
        ushort4 o;
        o.x = f2bf(v.x); o.y = f2bf(v.y); o.z = f2bf(v.z); o.w = f2bf(v.w);
        *(ushort4*)(out + i) = o;
    }
}

// ---------------- fp32 [K][Nin] -> bf16 [n_base+n][K] transpose ----------------
// Writes rows n in [0, Npad) of the output (offset by n_base); reads OOB -> 0.
__global__ __launch_bounds__(256) void transpose_f32_bf16(
    const float* __restrict__ in, ushort* __restrict__ out,
    int K, int Nin, int n_base, int Npad)
{
    __shared__ float tile[32][33];
    const int tx = threadIdx.x & 31;
    const int ty = threadIdx.x >> 5;   // 0..7
    const int n0 = blockIdx.x * 32;
    const int k0 = blockIdx.y * 32;
    #pragma unroll
    for (int i = 0; i < 4; i++) {
        int k = k0 + ty + i * 8;
        int n = n0 + tx;
        float v = (k < K && n < Nin) ? in[(size_t)k * Nin + n] : 0.0f;
        tile[ty + i * 8][tx] = v;
    }
    __syncthreads();
    #pragma unroll
    for (int i = 0; i < 4; i++) {
        int n = n0 + ty + i * 8;
        int k = k0 + tx;
        if (n < Npad && k < K)
            out[(size_t)(n_base + n) * K + k] = f2bf(tile[tx][ty + i * 8]);
    }
}

// ---------------- bf16 MFMA GEMM, 128x128 tile, BK=32 (m97 structure) ----------
// A: [M][K] bf16 row-major. Bt: [N][K] bf16 row-major (B transposed).
// mode 0: Cf[row*ldc+col] = acc (f32)
// mode 2: col<1024 -> Cb[row*1024+col] = bf16(relu(acc)); col>=1024 -> Cv[row*1024+col-1024] = acc
__global__ __launch_bounds__(256) void gemm_mfma(
    const ushort* __restrict__ A, const ushort* __restrict__ Bt, int K,
    float* __restrict__ Cf, ushort* __restrict__ Cb, float* __restrict__ Cv,
    int mode, int ldc)
{
    __shared__ ushort As[128 * 32];   // 8 KB
    __shared__ ushort Bs[128 * 32];   // 8 KB

    const int tid = threadIdx.x;
    const int wv  = tid >> 6;         // wave 0..3
    const int ln  = tid & 63;
    const int row0 = blockIdx.y * 128;
    const int col0 = blockIdx.x * 128;
    const int wr = (wv >> 1) * 64;    // wave row offset in tile
    const int wc = (wv & 1) * 64;     // wave col offset in tile

    f32x4 acc[4][4];
    #pragma unroll
    for (int i = 0; i < 4; i++)
        #pragma unroll
        for (int j = 0; j < 4; j++)
            acc[i][j] = (f32x4){0.f, 0.f, 0.f, 0.f};

    const int l15 = ln & 15;
    const int lq  = ln >> 4;          // 0..3

    for (int k0 = 0; k0 < K; k0 += 32) {
        // stage A and B tiles: 128 rows x 32 bf16 each; chunk = 16B, 4 chunks/row.
        #pragma unroll
        for (int r = 0; r < 2; ++r) {
            int c = r * 256 + tid;                 // chunk id 0..511
            const ushort* gA = A + (size_t)(row0 + (c >> 2)) * K + k0 + (c & 3) * 8;
            __builtin_amdgcn_global_load_lds(
                (const __attribute__((address_space(1))) void*)gA,
                (__attribute__((address_space(3))) void*)(As + r * 2048 + wv * 512),
                16, 0, 0);
        }
        #pragma unroll
        for (int r = 0; r < 2; ++r) {
            int c = r * 256 + tid;
            const ushort* gB = Bt + (size_t)(col0 + (c >> 2)) * K + k0 + (c & 3) * 8;
            __builtin_amdgcn_global_load_lds(
                (const __attribute__((address_space(1))) void*)gB,
                (__attribute__((address_space(3))) void*)(Bs + r * 2048 + wv * 512),
                16, 0, 0);
        }
        __syncthreads();

        bf16x8 af[4], bfr[4];
        #pragma unroll
        for (int mi = 0; mi < 4; mi++)
            af[mi] = *(const bf16x8*)&As[(wr + mi * 16 + l15) * 32 + lq * 8];
        #pragma unroll
        for (int ni = 0; ni < 4; ni++)
            bfr[ni] = *(const bf16x8*)&Bs[(wc + ni * 16 + l15) * 32 + lq * 8];
        #pragma unroll
        for (int mi = 0; mi < 4; mi++)
            #pragma unroll
            for (int ni = 0; ni < 4; ni++)
                acc[mi][ni] = __builtin_amdgcn_mfma_f32_16x16x32_bf16(
                    af[mi], bfr[ni], acc[mi][ni], 0, 0, 0);
        __syncthreads();
    }

    // Epilogue. D layout: col = lane&15, row = (lane>>4)*4 + reg.
    #pragma unroll
    for (int mi = 0; mi < 4; mi++) {
        #pragma unroll
        for (int ni = 0; ni < 4; ni++) {
            #pragma unroll
            for (int r = 0; r < 4; r++) {
                int row = row0 + wr + mi * 16 + lq * 4 + r;
                int col = col0 + wc + ni * 16 + l15;
                float v = acc[mi][ni][r];
                if (mode == 0) {
                    Cf[(size_t)row * ldc + col] = v;
                } else { // mode 2: qv split epilogue
                    if (col < DD) {
                        Cb[(size_t)row * DD + col] = f2bf(fmaxf(v, 0.0f));
                    } else {
                        Cv[(size_t)row * DD + (col - DD)] = v;
                    }
                }
            }
        }
    }
}

// ------------- Fused per-(b,t) softmax + sliding-window weighted sum -------------
// logits: [B*T, 256] f32 (cols 0..83 scale0 as [h][21]; cols 84..247 scale1 as [h][41])
// v: [B*T, D] f32.  x out: [B*T, D] bf16.
__global__ __launch_bounds__(256) void attn_window_kernel(
    const float* __restrict__ v,
    const float* __restrict__ logits,
    const float* __restrict__ scale_w,
    ushort* __restrict__ x)
{
    const int bt = blockIdx.x;
    const int b = bt >> 10;
    const int t = bt & 1023;

    __shared__ float a0[HPS][C0];
    __shared__ float a1[HPS][C1];
    __shared__ float sw[2];

    const int tid = threadIdx.x;

    if (tid == 0) {
        float s0 = scale_w[0], s1 = scale_w[1];
        float m = fmaxf(s0, s1);
        float e0 = __expf(s0 - m), e1 = __expf(s1 - m);
        float inv = 1.0f / (e0 + e1);
        sw[0] = e0 * inv;
        sw[1] = e1 * inv;
    }

    if (tid < HPS) {
        const float* L = logits + (size_t)bt * NL + tid * C0;
        float m = -1e30f;
        for (int j = 0; j < C0; j++) m = fmaxf(m, L[j]);
        float s = 0.0f;
        for (int j = 0; j < C0; j++) s += __expf(L[j] - m);
        float inv = 1.0f / s;
        for (int j = 0; j < C0; j++) a0[tid][j] = __expf(L[j] - m) * inv;
    } else if (tid >= HPS && tid < 2 * HPS) {
        int h = tid - HPS;
        const float* L = logits + (size_t)bt * NL + N0 + h * C1;
        float m = -1e30f;
        for (int j = 0; j < C1; j++) m = fmaxf(m, L[j]);
        float s = 0.0f;
        for (int j = 0; j < C1; j++) s += __expf(L[j] - m);
        float inv = 1.0f / s;
        for (int j = 0; j < C1; j++) a1[h][j] = __expf(L[j] - m) * inv;
    }
    __syncthreads();

    const int d = tid * 4;
    const int h = d >> 8;             // head (head_dim = 256)
    const float sw0 = sw[0], sw1 = sw[1];
    const float* vbase = v + (size_t)b * TT * DD + d;

    float4 acc = make_float4(0.f, 0.f, 0.f, 0.f);

    #pragma unroll
    for (int j = 0; j < C0; j++) {
        int tt = t + j - (C0 - 1) / 2;
        if (tt < 0 || tt >= TT) continue;
        float w = sw0 * a0[h][j];
        float4 vv = *(const float4*)(vbase + (size_t)tt * DD);
        acc.x = fmaf(w, vv.x, acc.x);
        acc.y = fmaf(w, vv.y, acc.y);
        acc.z = fmaf(w, vv.z, acc.z);
        acc.w = fmaf(w, vv.w, acc.w);
    }
    #pragma unroll
    for (int j = 0; j < C1; j++) {
        int tt = t + j - (C1 - 1) / 2;
        if (tt < 0 || tt >= TT) continue;
        float w = sw1 * a1[h][j];
        float4 vv = *(const float4*)(vbase + (size_t)tt * DD);
        acc.x = fmaf(w, vv.x, acc.x);
        acc.y = fmaf(w, vv.y, acc.y);
        acc.z = fmaf(w, vv.z, acc.z);
        acc.w = fmaf(w, vv.w, acc.w);
    }

    ushort4 o;
    o.x = f2bf(acc.x); o.y = f2bf(acc.y); o.z = f2bf(acc.z); o.w = f2bf(acc.w);
    *(ushort4*)(x + (size_t)bt * DD + d) = o;
}

// ---------------------------------- launch ----------------------------------
extern "C" void kernel_launch(void* const* d_in, const int* in_sizes, int n_in,
                              void* d_out, int out_size, void* d_ws, size_t ws_size,
                              hipStream_t stream)
{
    const float* query   = (const float*)d_in[0];
    const float* W_qv    = (const float*)d_in[3];
    const float* W2_0    = (const float*)d_in[4];
    const float* W2_1    = (const float*)d_in[5];
    const float* scale_w = (const float*)d_in[6];
    const float* W_out   = (const float*)d_in[7];
    float* out = (float*)d_out;

    // Workspace layout (bytes -> carve as char*)
    char* ws = (char*)d_ws;
    ushort* query_bf = (ushort*)ws;                 ws += (size_t)BT * DD * 2;        // 8 MB
    ushort* WqvT     = (ushort*)ws;                 ws += (size_t)2 * DD * DD * 2;    // 4 MB
    ushort* WoutT    = (ushort*)ws;                 ws += (size_t)DD * DD * 2;        // 2 MB
    ushort* W2T      = (ushort*)ws;                 ws += (size_t)NL * DD * 2;        // 0.5 MB
    ushort* reluq    = (ushort*)ws;                 ws += (size_t)BT * DD * 2;        // 8 MB
    float*  vbuf     = (float*)ws;                  ws += (size_t)BT * DD * 4;        // 16 MB
    float*  logits   = (float*)ws;                  ws += (size_t)BT * NL * 4;        // 4 MB
    ushort* xbuf     = (ushort*)ws;                 ws += (size_t)BT * DD * 2;        // 8 MB

    // 0) conversions
    f32_to_bf16<<<(BT * DD) / (256 * 4), 256, 0, stream>>>(query, query_bf, BT * DD);
    {   // W_qv [1024][2048] -> WqvT [2048][1024]
        dim3 g(2 * DD / 32, DD / 32);
        transpose_f32_bf16<<<g, 256, 0, stream>>>(W_qv, WqvT, DD, 2 * DD, 0, 2 * DD);
    }
    {   // W_out [1024][1024] -> WoutT [1024][1024]
        dim3 g(DD / 32, DD / 32);
        transpose_f32_bf16<<<g, 256, 0, stream>>>(W_out, WoutT, DD, DD, 0, DD);
    }
    {   // W2_0 [1024][84] -> W2T rows 0..83
        dim3 g((N0 + 31) / 32, DD / 32);
        transpose_f32_bf16<<<g, 256, 0, stream>>>(W2_0, W2T, DD, N0, 0, N0);
    }
    {   // W2_1 [1024][164] -> W2T rows 84..247, zeros 248..255
        dim3 g((NL - N0 + 31) / 32, DD / 32);
        transpose_f32_bf16<<<g, 256, 0, stream>>>(W2_1, W2T, DD, N1, N0, NL - N0);
    }

    // 1) qv GEMM: [4096,1024] x [1024,2048] -> reluq (bf16) + v (f32)
    {
        dim3 grid((2 * DD) / 128, BT / 128);
        gemm_mfma<<<grid, 256, 0, stream>>>(query_bf, WqvT, DD,
                                            nullptr, reluq, vbuf, 2, 0);
    }
    // 2) logits GEMM: relu(q) [4096,1024] x [1024,256] -> logits f32
    {
        dim3 grid(NL / 128, BT / 128);
        gemm_mfma<<<grid, 256, 0, stream>>>(reluq, W2T, DD,
                                            logits, nullptr, nullptr, 0, NL);
    }
    // 3) softmax + sliding window -> x (bf16)
    attn_window_kernel<<<BT, 256, 0, stream>>>(vbuf, logits, scale_w, xbuf);

    // 4) out GEMM: x [4096,1024] x [1024,1024] -> out f32
    {
        dim3 grid(DD / 128, BT / 128);
        gemm_mfma<<<grid, 256, 0, stream>>>(xbuf, WoutT, DD,
                                            out, nullptr, nullptr, 0, DD);
    }
}

// Round 3
// 225.180 us; speedup vs baseline: 4.3665x; 1.5139x over previous
//
#include <hip/hip_runtime.h>
#include <hip/hip_bf16.h>
#include <math.h>

// Problem dims (fixed by reference)
#define BB 4
#define TT 1024
#define DD 1024
#define HPS 4          // heads per scale
#define C0 21
#define C1 41
#define N0 (HPS * C0)  // 84
#define N1 (HPS * C1)  // 164
#define NL 256         // padded combined logits width (84 + 164 = 248 -> 256)
#define BT (BB * TT)   // 4096
#define TB 64          // t-tile for window kernel
#define HALO 20
#define HB (TB + 2 * HALO)  // 104 rows staged

typedef unsigned int uint;
typedef __bf16 bf16x8 __attribute__((ext_vector_type(8)));
typedef float f32x4 __attribute__((ext_vector_type(4)));

__device__ __forceinline__ ushort f2bf(float f) {
    union { float f; uint u; } v; v.f = f;
    uint u = v.u;
    uint r = (u + 0x7FFFu + ((u >> 16) & 1u)) >> 16;
    return (ushort)r;
}
__device__ __forceinline__ float bf2f(ushort s) {
    union { uint u; float f; } v; v.u = ((uint)s) << 16;
    return v.f;
}

// ---------------- fp32 -> bf16 row copy (query) ----------------
__global__ __launch_bounds__(256) void f32_to_bf16(const float* __restrict__ in,
                                                   ushort* __restrict__ out, int n) {
    int i = (blockIdx.x * 256 + threadIdx.x) * 4;
    if (i < n) {
        float4 v = *(const float4*)(in + i);
        ushort4 o;
        o.x = f2bf(v.x); o.y = f2bf(v.y); o.z = f2bf(v.z); o.w = f2bf(v.w);
        *(ushort4*)(out + i) = o;
    }
}

// ---------------- fp32 [K][Nin] -> bf16 [n_base+n][K] transpose ----------------
__global__ __launch_bounds__(256) void transpose_f32_bf16(
    const float* __restrict__ in, ushort* __restrict__ out,
    int K, int Nin, int n_base, int Npad)
{
    __shared__ float tile[32][33];
    const int tx = threadIdx.x & 31;
    const int ty = threadIdx.x >> 5;   // 0..7
    const int n0 = blockIdx.x * 32;
    const int k0 = blockIdx.y * 32;
    #pragma unroll
    for (int i = 0; i < 4; i++) {
        int k = k0 + ty + i * 8;
        int n = n0 + tx;
        float v = (k < K && n < Nin) ? in[(size_t)k * Nin + n] : 0.0f;
        tile[ty + i * 8][tx] = v;
    }
    __syncthreads();
    #pragma unroll
    for (int i = 0; i < 4; i++) {
        int n = n0 + ty + i * 8;
        int k = k0 + tx;
        if (n < Npad && k < K)
            out[(size_t)(n_base + n) * K + k] = f2bf(tile[tx][ty + i * 8]);
    }
}

// ---------------- bf16 MFMA GEMM, 128x128 tile, BK=32 (m97 structure) ----------
// A: [M][K] bf16 row-major. Bt: [N][K] bf16 row-major (B transposed).
// mode 0: Cf[row*ldc+col] = acc (f32)
// mode 2: col<1024 -> Cb[row*1024+col] = bf16(relu(acc)); col>=1024 -> Cv = bf16(acc)
__global__ __launch_bounds__(256) void gemm_mfma(
    const ushort* __restrict__ A, const ushort* __restrict__ Bt, int K,
    float* __restrict__ Cf, ushort* __restrict__ Cb, ushort* __restrict__ Cv,
    int mode, int ldc)
{
    __shared__ ushort As[128 * 32];   // 8 KB
    __shared__ ushort Bs[128 * 32];   // 8 KB

    const int tid = threadIdx.x;
    const int wv  = tid >> 6;         // wave 0..3
    const int ln  = tid & 63;
    const int row0 = blockIdx.y * 128;
    const int col0 = blockIdx.x * 128;
    const int wr = (wv >> 1) * 64;
    const int wc = (wv & 1) * 64;

    f32x4 acc[4][4];
    #pragma unroll
    for (int i = 0; i < 4; i++)
        #pragma unroll
        for (int j = 0; j < 4; j++)
            acc[i][j] = (f32x4){0.f, 0.f, 0.f, 0.f};

    const int l15 = ln & 15;
    const int lq  = ln >> 4;          // 0..3

    for (int k0 = 0; k0 < K; k0 += 32) {
        #pragma unroll
        for (int r = 0; r < 2; ++r) {
            int c = r * 256 + tid;
            const ushort* gA = A + (size_t)(row0 + (c >> 2)) * K + k0 + (c & 3) * 8;
            __builtin_amdgcn_global_load_lds(
                (const __attribute__((address_space(1))) void*)gA,
                (__attribute__((address_space(3))) void*)(As + r * 2048 + wv * 512),
                16, 0, 0);
        }
        #pragma unroll
        for (int r = 0; r < 2; ++r) {
            int c = r * 256 + tid;
            const ushort* gB = Bt + (size_t)(col0 + (c >> 2)) * K + k0 + (c & 3) * 8;
            __builtin_amdgcn_global_load_lds(
                (const __attribute__((address_space(1))) void*)gB,
                (__attribute__((address_space(3))) void*)(Bs + r * 2048 + wv * 512),
                16, 0, 0);
        }
        __syncthreads();

        bf16x8 af[4], bfr[4];
        #pragma unroll
        for (int mi = 0; mi < 4; mi++)
            af[mi] = *(const bf16x8*)&As[(wr + mi * 16 + l15) * 32 + lq * 8];
        #pragma unroll
        for (int ni = 0; ni < 4; ni++)
            bfr[ni] = *(const bf16x8*)&Bs[(wc + ni * 16 + l15) * 32 + lq * 8];
        #pragma unroll
        for (int mi = 0; mi < 4; mi++)
            #pragma unroll
            for (int ni = 0; ni < 4; ni++)
                acc[mi][ni] = __builtin_amdgcn_mfma_f32_16x16x32_bf16(
                    af[mi], bfr[ni], acc[mi][ni], 0, 0, 0);
        __syncthreads();
    }

    // Epilogue. D layout: col = lane&15, row = (lane>>4)*4 + reg.
    #pragma unroll
    for (int mi = 0; mi < 4; mi++) {
        #pragma unroll
        for (int ni = 0; ni < 4; ni++) {
            #pragma unroll
            for (int r = 0; r < 4; r++) {
                int row = row0 + wr + mi * 16 + lq * 4 + r;
                int col = col0 + wc + ni * 16 + l15;
                float v = acc[mi][ni][r];
                if (mode == 0) {
                    Cf[(size_t)row * ldc + col] = v;
                } else { // mode 2: qv split epilogue
                    if (col < DD) {
                        Cb[(size_t)row * DD + col] = f2bf(fmaxf(v, 0.0f));
                    } else {
                        Cv[(size_t)row * DD + (col - DD)] = f2bf(v);
                    }
                }
            }
        }
    }
}

// ------------- Tiled window kernel: block = (b, t-tile of 64, head) -------------
// v: [BT][DD] bf16. logits: [BT][NL] f32. x: [BT][DD] bf16.
__global__ __launch_bounds__(256) void attn_window_kernel(
    const ushort* __restrict__ v,
    const float* __restrict__ logits,
    const float* __restrict__ scale_w,
    ushort* __restrict__ x)
{
    const int blk = blockIdx.x;       // 256 blocks
    const int h  = blk & 3;
    const int tt = (blk >> 2) & 15;
    const int b  = blk >> 6;
    const int t0 = tt * TB;
    const int tid = threadIdx.x;

    __shared__ ushort vs[HB][256];    // 53,248 B
    __shared__ float  cw[TB][42];     // 10,752 B (41 taps, pad to 42)

    // ---- stage v slab: rows t0-20 .. t0+83, this head's 256-wide slice ----
    const ushort* vb = v + (size_t)b * TT * DD + h * 256;
    #pragma unroll
    for (int i = 0; i < 13; i++) {
        int c = i * 256 + tid;        // chunk 0..3327 (16B chunks)
        int r = c >> 5;               // row 0..103
        int cir = c & 31;             // 16B chunk within row
        int t = t0 - HALO + r;
        uint4 val = make_uint4(0, 0, 0, 0);
        if (t >= 0 && t < TT)
            val = *(const uint4*)(vb + (size_t)t * DD + cir * 8);
        *(uint4*)(&vs[r][cir * 8]) = val;
    }

    // ---- combined 41-tap weights for 64 t's (threads 0..63) ----
    if (tid < TB) {
        const int t = t0 + tid;
        const int bt = b * TT + t;
        const float* L = logits + (size_t)bt * NL;

        float s0 = scale_w[0], s1 = scale_w[1];
        float mm = fmaxf(s0, s1);
        float e0 = __expf(s0 - mm), e1 = __expf(s1 - mm);
        float inv01 = 1.0f / (e0 + e1);
        float sw0 = e0 * inv01, sw1 = e1 * inv01;

        float w0[C0], w1[C1];
        {
            const float* L0 = L + h * C0;
            float m = -1e30f;
            #pragma unroll
            for (int j = 0; j < C0; j++) m = fmaxf(m, L0[j]);
            float s = 0.0f;
            #pragma unroll
            for (int j = 0; j < C0; j++) { w0[j] = __expf(L0[j] - m); s += w0[j]; }
            float inv = sw0 / s;
            #pragma unroll
            for (int j = 0; j < C0; j++) w0[j] *= inv;
        }
        {
            const float* L1 = L + N0 + h * C1;
            float m = -1e30f;
            #pragma unroll
            for (int j = 0; j < C1; j++) m = fmaxf(m, L1[j]);
            float s = 0.0f;
            #pragma unroll
            for (int j = 0; j < C1; j++) { w1[j] = __expf(L1[j] - m); s += w1[j]; }
            float inv = sw1 / s;
            #pragma unroll
            for (int j = 0; j < C1; j++) w1[j] *= inv;
        }
        #pragma unroll
        for (int o = 0; o < C1; o++) {
            float w = w1[o];
            if (o >= 10 && o <= 30) w += w0[o - 10];
            cw[tid][o] = w;
        }
    }
    __syncthreads();

    // ---- compute: thread (tq, dg) handles t' in [tq*16, +16), d = dg*4 ----
    const int tq = tid >> 6;          // 0..3 (wave id)
    const int dg = tid & 63;          // 0..63
    const int d  = dg * 4;

    for (int tloc = 0; tloc < 16; tloc++) {
        const int tp = tq * 16 + tloc;            // 0..63
        f32x4 acc = {0.f, 0.f, 0.f, 0.f};
        #pragma unroll
        for (int o = 0; o < C1; o++) {
            float w = cw[tp][o];
            ushort4 vv = *(const ushort4*)(&vs[tp + o][d]);
            acc[0] = fmaf(w, bf2f(vv.x), acc[0]);
            acc[1] = fmaf(w, bf2f(vv.y), acc[1]);
            acc[2] = fmaf(w, bf2f(vv.z), acc[2]);
            acc[3] = fmaf(w, bf2f(vv.w), acc[3]);
        }
        const int bt = b * TT + t0 + tp;
        ushort4 o4;
        o4.x = f2bf(acc[0]); o4.y = f2bf(acc[1]);
        o4.z = f2bf(acc[2]); o4.w = f2bf(acc[3]);
        *(ushort4*)(x + (size_t)bt * DD + h * 256 + d) = o4;
    }
}

// ---------------------------------- launch ----------------------------------
extern "C" void kernel_launch(void* const* d_in, const int* in_sizes, int n_in,
                              void* d_out, int out_size, void* d_ws, size_t ws_size,
                              hipStream_t stream)
{
    const float* query   = (const float*)d_in[0];
    const float* W_qv    = (const float*)d_in[3];
    const float* W2_0    = (const float*)d_in[4];
    const float* W2_1    = (const float*)d_in[5];
    const float* scale_w = (const float*)d_in[6];
    const float* W_out   = (const float*)d_in[7];
    float* out = (float*)d_out;

    // Workspace layout
    char* ws = (char*)d_ws;
    ushort* query_bf = (ushort*)ws;                 ws += (size_t)BT * DD * 2;        // 8 MB
    ushort* WqvT     = (ushort*)ws;                 ws += (size_t)2 * DD * DD * 2;    // 4 MB
    ushort* WoutT    = (ushort*)ws;                 ws += (size_t)DD * DD * 2;        // 2 MB
    ushort* W2T      = (ushort*)ws;                 ws += (size_t)NL * DD * 2;        // 0.5 MB
    ushort* reluq    = (ushort*)ws;                 ws += (size_t)BT * DD * 2;        // 8 MB
    ushort* vbuf     = (ushort*)ws;                 ws += (size_t)BT * DD * 2;        // 8 MB
    float*  logits   = (float*)ws;                  ws += (size_t)BT * NL * 4;        // 4 MB
    ushort* xbuf     = (ushort*)ws;                 ws += (size_t)BT * DD * 2;        // 8 MB

    // 0) conversions
    f32_to_bf16<<<(BT * DD) / (256 * 4), 256, 0, stream>>>(query, query_bf, BT * DD);
    {   dim3 g(2 * DD / 32, DD / 32);
        transpose_f32_bf16<<<g, 256, 0, stream>>>(W_qv, WqvT, DD, 2 * DD, 0, 2 * DD); }
    {   dim3 g(DD / 32, DD / 32);
        transpose_f32_bf16<<<g, 256, 0, stream>>>(W_out, WoutT, DD, DD, 0, DD); }
    {   dim3 g((N0 + 31) / 32, DD / 32);
        transpose_f32_bf16<<<g, 256, 0, stream>>>(W2_0, W2T, DD, N0, 0, N0); }
    {   dim3 g((NL - N0 + 31) / 32, DD / 32);
        transpose_f32_bf16<<<g, 256, 0, stream>>>(W2_1, W2T, DD, N1, N0, NL - N0); }

    // 1) qv GEMM -> reluq (bf16) + v (bf16)
    {   dim3 grid((2 * DD) / 128, BT / 128);
        gemm_mfma<<<grid, 256, 0, stream>>>(query_bf, WqvT, DD,
                                            nullptr, reluq, vbuf, 2, 0); }
    // 2) logits GEMM: relu(q) x W2T -> logits f32
    {   dim3 grid(NL / 128, BT / 128);
        gemm_mfma<<<grid, 256, 0, stream>>>(reluq, W2T, DD,
                                            logits, nullptr, nullptr, 0, NL); }
    // 3) softmax + sliding window -> x (bf16)
    attn_window_kernel<<<256, 256, 0, stream>>>(vbuf, logits, scale_w, xbuf);

    // 4) out GEMM: x x WoutT -> out f32
    {   dim3 grid(DD / 128, BT / 128);
        gemm_mfma<<<grid, 256, 0, stream>>>(xbuf, WoutT, DD,
                                            out, nullptr, nullptr, 0, DD); }
}